// Round 1
// baseline (2141.477 us; speedup 1.0000x reference)
//
#include <hip/hip_runtime.h>
#include <hip/hip_bf16.h>

#define NN 50000      // nodes
#define NE 500000     // edges (without self loops)
#define EP (NE + NN)  // edges with self loops
#define NB 50         // graphs
#define NEG 0.2f

// ---------- helpers: order-preserving f32 <-> u32 for atomicMax ----------
__device__ __forceinline__ unsigned f2ord(float f) {
  unsigned u = __float_as_uint(f);
  return (u & 0x80000000u) ? ~u : (u | 0x80000000u);
}
__device__ __forceinline__ float ord2f(unsigned u) {
  return __uint_as_float((u & 0x80000000u) ? (u & 0x7FFFFFFFu) : ~u);
}

// ---------- mean(edge_attr) : sum into esum[0] ----------
__global__ __launch_bounds__(256) void reduce_sum_kernel(const float* __restrict__ ea,
                                                         float* __restrict__ esum) {
  int t = blockIdx.x * 256 + threadIdx.x;
  float v = 0.f;
  for (int i = t; i < NE; i += gridDim.x * 256) v += ea[i];
  for (int off = 1; off < 64; off <<= 1) v += __shfl_xor(v, off, 64);
  if ((threadIdx.x & 63) == 0) atomicAdd(esum, v);
}

// ---------- encoder: h0[n][j] = relu(x[n,:8] @ enc_w + enc_b) ----------
__global__ __launch_bounds__(256) void encoder_kernel(const float* __restrict__ x,
                                                      const float* __restrict__ w,
                                                      const float* __restrict__ b,
                                                      float* __restrict__ h0) {
  int t = blockIdx.x * 256 + threadIdx.x;
  if (t >= NN * 64) return;
  int n = t >> 6, j = t & 63;
  float acc = b[j];
#pragma unroll
  for (int k = 0; k < 8; k++) acc += x[n * 8 + k] * w[k * 64 + j];
  h0[t] = fmaxf(acc, 0.f);
}

// ---------- linear: C[n][j] = A[n,:K] @ W[:,j] + bias[j]   (256 cols) ----------
// 256 threads = 256 output columns; 16 rows per block. A-row addresses are
// wave-uniform -> scalar loads; W reads are coalesced across threads.
__global__ __launch_bounds__(256) void linear_kernel(const float* __restrict__ A, int K,
                                                     const float* __restrict__ W,
                                                     const float* __restrict__ bias,
                                                     float* __restrict__ C) {
  int j = threadIdx.x;
  int n0 = blockIdx.x * 16;
  float acc[16];
#pragma unroll
  for (int m = 0; m < 16; m++) acc[m] = 0.f;
  const float* Arow = A + (size_t)n0 * K;
  for (int k = 0; k < K; k += 4) {
    float w0 = W[(size_t)(k + 0) * 256 + j];
    float w1 = W[(size_t)(k + 1) * 256 + j];
    float w2 = W[(size_t)(k + 2) * 256 + j];
    float w3 = W[(size_t)(k + 3) * 256 + j];
#pragma unroll
    for (int m = 0; m < 16; m++) {
      const float* a = Arow + (size_t)m * K + k;
      acc[m] += a[0] * w0 + a[1] * w1 + a[2] * w2 + a[3] * w3;
    }
  }
  float bv = bias[j];
#pragma unroll
  for (int m = 0; m < 16; m++) C[(size_t)(n0 + m) * 256 + j] = acc[m] + bv;
}

// ---------- edge pass 1: logits + segment max ----------
// one wave per edge; lane handles elements q*64+lane (q = head)
__global__ __launch_bounds__(256) void edge_logits_kernel(const int* __restrict__ ei,
                                                          const float* __restrict__ ea,
                                                          const float* __restrict__ esum,
                                                          const float* __restrict__ xl,
                                                          const float* __restrict__ xr,
                                                          const float* __restrict__ we,
                                                          const float* __restrict__ att,
                                                          float* __restrict__ logits,
                                                          unsigned* __restrict__ lmax) {
  int w = threadIdx.x >> 6;
  int lane = threadIdx.x & 63;
  int e = blockIdx.x * 4 + w;
  if (e >= EP) return;
  int src, dst;
  float eav;
  if (e < NE) {
    src = ei[e];
    dst = ei[NE + e];
    eav = ea[e];
  } else {
    src = dst = e - NE;
    eav = esum[0] * (1.0f / NE);
  }
  const float* pxl = xl + (size_t)src * 256;
  const float* pxr = xr + (size_t)dst * 256;
  float p[4];
#pragma unroll
  for (int q = 0; q < 4; q++) {
    int idx = q * 64 + lane;
    float v = pxl[idx] + pxr[idx] + eav * we[idx];
    v = v > 0.f ? v : NEG * v;
    p[q] = v * att[idx];
  }
#pragma unroll
  for (int q = 0; q < 4; q++)
    for (int off = 1; off < 64; off <<= 1) p[q] += __shfl_xor(p[q], off, 64);
  if (lane == 0) {
#pragma unroll
    for (int q = 0; q < 4; q++) {
      logits[(size_t)e * 4 + q] = p[q];
      atomicMax(&lmax[(size_t)dst * 4 + q], f2ord(p[q]));
    }
  }
}

// ---------- edge pass 2 (fused): ex = exp(logit - lmax[dst]); den += ex;
//            agg_unnorm[dst] += xl[src] * ex  ----------
__global__ __launch_bounds__(256) void edge_agg_kernel(const int* __restrict__ ei,
                                                       const float* __restrict__ logits,
                                                       const unsigned* __restrict__ lmax,
                                                       const float* __restrict__ xl,
                                                       float* __restrict__ den,
                                                       float* __restrict__ agg) {
  int w = threadIdx.x >> 6;
  int lane = threadIdx.x & 63;
  int e = blockIdx.x * 4 + w;
  if (e >= EP) return;
  int src, dst;
  if (e < NE) {
    src = ei[e];
    dst = ei[NE + e];
  } else {
    src = dst = e - NE;
  }
  float ex0 = __expf(logits[(size_t)e * 4 + 0] - ord2f(lmax[(size_t)dst * 4 + 0]));
  float ex1 = __expf(logits[(size_t)e * 4 + 1] - ord2f(lmax[(size_t)dst * 4 + 1]));
  float ex2 = __expf(logits[(size_t)e * 4 + 2] - ord2f(lmax[(size_t)dst * 4 + 2]));
  float ex3 = __expf(logits[(size_t)e * 4 + 3] - ord2f(lmax[(size_t)dst * 4 + 3]));
  if (lane == 0) {
    atomicAdd(&den[(size_t)dst * 4 + 0], ex0);
    atomicAdd(&den[(size_t)dst * 4 + 1], ex1);
    atomicAdd(&den[(size_t)dst * 4 + 2], ex2);
    atomicAdd(&den[(size_t)dst * 4 + 3], ex3);
  }
  const float* pxl = xl + (size_t)src * 256;
  float* pag = agg + (size_t)dst * 256;
  atomicAdd(&pag[lane], pxl[lane] * ex0);
  atomicAdd(&pag[64 + lane], pxl[64 + lane] * ex1);
  atomicAdd(&pag[128 + lane], pxl[128 + lane] * ex2);
  atomicAdd(&pag[192 + lane], pxl[192 + lane] * ex3);
}

// ---------- normalize + bias + relu (in place on agg) ----------
__global__ __launch_bounds__(256) void norm_bias_relu_kernel(float* __restrict__ agg,
                                                             const float* __restrict__ den,
                                                             const float* __restrict__ bias) {
  int t = blockIdx.x * 256 + threadIdx.x;
  if (t >= NN * 256) return;
  int n = t >> 8, idx = t & 255;
  float d = den[(size_t)n * 4 + (idx >> 6)];
  float v = agg[t] / d + bias[idx];
  agg[t] = fmaxf(v, 0.f);
}

// ---------- global mean pool (batch is sorted; run-length flush) ----------
__global__ __launch_bounds__(256) void pool_kernel(const float* __restrict__ h,
                                                   const int* __restrict__ batch,
                                                   float* __restrict__ sums,
                                                   float* __restrict__ cnts) {
  __shared__ int sb[128];
  int n0 = blockIdx.x * 128;
  int j = threadIdx.x;
  int count = min(128, NN - n0);
  if (count <= 0) return;
  for (int t = threadIdx.x; t < count; t += 256) sb[t] = batch[n0 + t];
  __syncthreads();
  float acc = 0.f;
  int run = 0;
  int cur = sb[0];
  for (int i = 0; i < count; ++i) {
    int b = sb[i];
    if (b != cur) {
      atomicAdd(&sums[(size_t)cur * 256 + j], acc);
      if (j == 0) atomicAdd(&cnts[cur], (float)run);
      acc = 0.f;
      run = 0;
      cur = b;
    }
    acc += h[(size_t)(n0 + i) * 256 + j];
    run++;
  }
  atomicAdd(&sums[(size_t)cur * 256 + j], acc);
  if (j == 0) atomicAdd(&cnts[cur], (float)run);
}

// ---------- post-MLP head: one block per graph ----------
__global__ __launch_bounds__(128) void head_kernel(const float* __restrict__ sums,
                                                   const float* __restrict__ cnts,
                                                   const float* __restrict__ p1_w,
                                                   const float* __restrict__ p1_b,
                                                   const float* __restrict__ ln_g,
                                                   const float* __restrict__ ln_b,
                                                   const float* __restrict__ p2_w,
                                                   const float* __restrict__ p2_b,
                                                   const float* __restrict__ hc_w,
                                                   const float* __restrict__ hc_b,
                                                   const float* __restrict__ hf_w,
                                                   const float* __restrict__ hf_b,
                                                   float* __restrict__ out) {
  int g = blockIdx.x;
  int j = threadIdx.x;  // 0..127
  __shared__ float sp[256], st[128], sz[64];
  float cnt = fmaxf(cnts[g], 1.0f);
  for (int t = j; t < 256; t += 128) sp[t] = sums[(size_t)g * 256 + t] / cnt;
  __syncthreads();
  float acc = p1_b[j];
  for (int k = 0; k < 256; k++) acc += sp[k] * p1_w[(size_t)k * 128 + j];
  st[j] = acc;
  __syncthreads();
  float mu = 0.f;
  for (int k = 0; k < 128; k++) mu += st[k];
  mu *= (1.f / 128.f);
  float var = 0.f;
  for (int k = 0; k < 128; k++) {
    float d = st[k] - mu;
    var += d * d;
  }
  var *= (1.f / 128.f);
  float tj = (acc - mu) * rsqrtf(var + 1e-5f) * ln_g[j] + ln_b[j];
  tj = fmaxf(tj, 0.f);
  __syncthreads();
  st[j] = tj;
  __syncthreads();
  if (j < 64) {
    float z = p2_b[j];
    for (int k = 0; k < 128; k++) z += st[k] * p2_w[(size_t)k * 64 + j];
    z = fmaxf(z, 0.f);
    sz[j] = z;
    out[500 + (size_t)g * 64 + j] = z;  // output 2: z [B,64]
  }
  __syncthreads();
  if (j == 0) {
    float c = hc_b[0];
    for (int k = 0; k < 64; k++) c += sz[k] * hc_w[k];
    out[g] = c;  // output 0: cooling [B]
  }
  if (j >= 1 && j < 10) {
    int f = j - 1;
    float v = hf_b[f];
    for (int k = 0; k < 64; k++) v += sz[k] * hf_w[(size_t)k * 9 + f];
    out[50 + (size_t)g * 9 + f] = v;  // output 1: fatigue [B,9]
  }
}

extern "C" void kernel_launch(void* const* d_in, const int* in_sizes, int n_in,
                              void* d_out, int out_size, void* d_ws, size_t ws_size,
                              hipStream_t stream) {
  const float* x = (const float*)d_in[0];
  const int* ei = (const int*)d_in[1];
  const float* ea = (const float*)d_in[2];
  const int* batch = (const int*)d_in[3];
  const float* enc_w = (const float*)d_in[4];
  const float* enc_b = (const float*)d_in[5];
  const float* g1_wl = (const float*)d_in[6];
  const float* g1_bl = (const float*)d_in[7];
  const float* g1_wr = (const float*)d_in[8];
  const float* g1_br = (const float*)d_in[9];
  const float* g1_we = (const float*)d_in[10];
  const float* g1_att = (const float*)d_in[11];
  const float* g1_bias = (const float*)d_in[12];
  const float* g2_wl = (const float*)d_in[13];
  const float* g2_bl = (const float*)d_in[14];
  const float* g2_wr = (const float*)d_in[15];
  const float* g2_br = (const float*)d_in[16];
  const float* g2_we = (const float*)d_in[17];
  const float* g2_att = (const float*)d_in[18];
  const float* g2_bias = (const float*)d_in[19];
  const float* p1_w = (const float*)d_in[20];
  const float* p1_b = (const float*)d_in[21];
  const float* ln_g = (const float*)d_in[22];
  const float* ln_b = (const float*)d_in[23];
  const float* p2_w = (const float*)d_in[24];
  const float* p2_b = (const float*)d_in[25];
  const float* hc_w = (const float*)d_in[26];
  const float* hc_b = (const float*)d_in[27];
  const float* hf_w = (const float*)d_in[28];
  const float* hf_b = (const float*)d_in[29];
  float* out = (float*)d_out;

  // ---- workspace layout (floats) ----
  float* ws = (float*)d_ws;
  float* buf1 = ws;                         // N*256 (h0 lives in first N*64, then agg/h)
  float* xl = buf1 + (size_t)NN * 256;      // N*256
  float* xr = xl + (size_t)NN * 256;        // N*256
  float* logits = xr + (size_t)NN * 256;    // EP*4
  unsigned* lmax = (unsigned*)(logits + (size_t)EP * 4);  // N*4
  float* den = (float*)(lmax + (size_t)NN * 4);           // N*4
  float* sums = den + (size_t)NN * 4;       // B*256
  float* cnts = sums + (size_t)NB * 256;    // B
  float* esum = cnts + NB;                  // 1

  // ---- edge_attr mean ----
  hipMemsetAsync(esum, 0, sizeof(float), stream);
  reduce_sum_kernel<<<256, 256, 0, stream>>>(ea, esum);

  // ---- encoder ----
  encoder_kernel<<<(NN * 64 + 255) / 256, 256, 0, stream>>>(x, enc_w, enc_b, buf1);

  const int nEdgeBlocks = (EP + 3) / 4;

  // ================= GAT layer 1 (K=64) =================
  linear_kernel<<<NN / 16, 256, 0, stream>>>(buf1, 64, g1_wl, g1_bl, xl);
  linear_kernel<<<NN / 16, 256, 0, stream>>>(buf1, 64, g1_wr, g1_br, xr);
  hipMemsetAsync(buf1, 0, (size_t)NN * 256 * sizeof(float), stream);
  hipMemsetAsync(lmax, 0, (size_t)NN * 4 * sizeof(unsigned), stream);
  hipMemsetAsync(den, 0, (size_t)NN * 4 * sizeof(float), stream);
  edge_logits_kernel<<<nEdgeBlocks, 256, 0, stream>>>(ei, ea, esum, xl, xr, g1_we, g1_att,
                                                      logits, lmax);
  edge_agg_kernel<<<nEdgeBlocks, 256, 0, stream>>>(ei, logits, lmax, xl, den, buf1);
  norm_bias_relu_kernel<<<(NN * 256 + 255) / 256, 256, 0, stream>>>(buf1, den, g1_bias);

  // ================= GAT layer 2 (K=256) =================
  linear_kernel<<<NN / 16, 256, 0, stream>>>(buf1, 256, g2_wl, g2_bl, xl);
  linear_kernel<<<NN / 16, 256, 0, stream>>>(buf1, 256, g2_wr, g2_br, xr);
  hipMemsetAsync(buf1, 0, (size_t)NN * 256 * sizeof(float), stream);
  hipMemsetAsync(lmax, 0, (size_t)NN * 4 * sizeof(unsigned), stream);
  hipMemsetAsync(den, 0, (size_t)NN * 4 * sizeof(float), stream);
  edge_logits_kernel<<<nEdgeBlocks, 256, 0, stream>>>(ei, ea, esum, xl, xr, g2_we, g2_att,
                                                      logits, lmax);
  edge_agg_kernel<<<nEdgeBlocks, 256, 0, stream>>>(ei, logits, lmax, xl, den, buf1);
  norm_bias_relu_kernel<<<(NN * 256 + 255) / 256, 256, 0, stream>>>(buf1, den, g2_bias);

  // ================= pool + head =================
  hipMemsetAsync(sums, 0, (size_t)NB * 256 * sizeof(float), stream);
  hipMemsetAsync(cnts, 0, (size_t)NB * sizeof(float), stream);
  pool_kernel<<<(NN + 127) / 128, 256, 0, stream>>>(buf1, batch, sums, cnts);
  head_kernel<<<NB, 128, 0, stream>>>(sums, cnts, p1_w, p1_b, ln_g, ln_b, p2_w, p2_b,
                                      hc_w, hc_b, hf_w, hf_b, out);
}

// Round 2
// 889.578 us; speedup vs baseline: 2.4073x; 2.4073x over previous
//
#include <hip/hip_runtime.h>
#include <hip/hip_bf16.h>

#define NN 50000      // nodes
#define NE 500000     // edges (without self loops)
#define EP (NE + NN)  // edges with self loops
#define NB 50         // graphs
#define NEG 0.2f
#define NBLK_SCAN 196  // ceil(NN/256)

// ---------- mean(edge_attr) : sum into esum[0] ----------
__global__ __launch_bounds__(256) void reduce_sum_kernel(const float* __restrict__ ea,
                                                         float* __restrict__ esum) {
  int t = blockIdx.x * 256 + threadIdx.x;
  float v = 0.f;
  for (int i = t; i < NE; i += gridDim.x * 256) v += ea[i];
  for (int off = 1; off < 64; off <<= 1) v += __shfl_xor(v, off, 64);
  if ((threadIdx.x & 63) == 0) atomicAdd(esum, v);
}

// ---------- encoder: h0[n][j] = relu(x[n,:8] @ enc_w + enc_b) ----------
__global__ __launch_bounds__(256) void encoder_kernel(const float* __restrict__ x,
                                                      const float* __restrict__ w,
                                                      const float* __restrict__ b,
                                                      float* __restrict__ h0) {
  int t = blockIdx.x * 256 + threadIdx.x;
  if (t >= NN * 64) return;
  int n = t >> 6, j = t & 63;
  float acc = b[j];
#pragma unroll
  for (int k = 0; k < 8; k++) acc += x[n * 8 + k] * w[k * 64 + j];
  h0[t] = fmaxf(acc, 0.f);
}

// ---------- linear: C[n][j] = A[n,:K] @ W[:,j] + bias[j]   (256 cols) ----------
__global__ __launch_bounds__(256) void linear_kernel(const float* __restrict__ A, int K,
                                                     const float* __restrict__ W,
                                                     const float* __restrict__ bias,
                                                     float* __restrict__ C) {
  int j = threadIdx.x;
  int n0 = blockIdx.x * 16;
  float acc[16];
#pragma unroll
  for (int m = 0; m < 16; m++) acc[m] = 0.f;
  const float* Arow = A + (size_t)n0 * K;
  for (int k = 0; k < K; k += 4) {
    float w0 = W[(size_t)(k + 0) * 256 + j];
    float w1 = W[(size_t)(k + 1) * 256 + j];
    float w2 = W[(size_t)(k + 2) * 256 + j];
    float w3 = W[(size_t)(k + 3) * 256 + j];
#pragma unroll
    for (int m = 0; m < 16; m++) {
      const float* a = Arow + (size_t)m * K + k;
      acc[m] += a[0] * w0 + a[1] * w1 + a[2] * w2 + a[3] * w3;
    }
  }
  float bv = bias[j];
#pragma unroll
  for (int m = 0; m < 16; m++) C[(size_t)(n0 + m) * 256 + j] = acc[m] + bv;
}

// ================= counting sort of edges by dst =================
__global__ __launch_bounds__(256) void hist_kernel(const int* __restrict__ ei,
                                                   int* __restrict__ counts) {
  int t = blockIdx.x * 256 + threadIdx.x;
  for (int e = t; e < EP; e += gridDim.x * 256) {
    int dst = (e < NE) ? ei[NE + e] : e - NE;
    atomicAdd(&counts[dst], 1);
  }
}

__global__ __launch_bounds__(256) void scanA_kernel(const int* __restrict__ counts,
                                                    int* __restrict__ bsum) {
  int i = blockIdx.x * 256 + threadIdx.x;
  int v = (i < NN) ? counts[i] : 0;
  for (int off = 1; off < 64; off <<= 1) v += __shfl_xor(v, off, 64);
  __shared__ int sw[4];
  if ((threadIdx.x & 63) == 0) sw[threadIdx.x >> 6] = v;
  __syncthreads();
  if (threadIdx.x == 0) bsum[blockIdx.x] = sw[0] + sw[1] + sw[2] + sw[3];
}

__global__ void scanB_kernel(int* __restrict__ bsum) {
  if (threadIdx.x == 0 && blockIdx.x == 0) {
    int run = 0;
    for (int b = 0; b < NBLK_SCAN; b++) {
      int v = bsum[b];
      bsum[b] = run;
      run += v;
    }
  }
}

__global__ __launch_bounds__(256) void scanC_kernel(const int* __restrict__ counts,
                                                    const int* __restrict__ bpre,
                                                    int* __restrict__ offsets,
                                                    int* __restrict__ cursor) {
  __shared__ int s[256];
  int i = blockIdx.x * 256 + threadIdx.x;
  int v = (i < NN) ? counts[i] : 0;
  s[threadIdx.x] = v;
  __syncthreads();
  for (int off = 1; off < 256; off <<= 1) {
    int add = (threadIdx.x >= off) ? s[threadIdx.x - off] : 0;
    __syncthreads();
    s[threadIdx.x] += add;
    __syncthreads();
  }
  if (i < NN) {
    int excl = s[threadIdx.x] - v + bpre[blockIdx.x];
    offsets[i] = excl;
    cursor[i] = excl;
  }
}

__global__ __launch_bounds__(256) void scatter_kernel(const int* __restrict__ ei,
                                                      const float* __restrict__ ea,
                                                      const float* __restrict__ esum,
                                                      int* __restrict__ cursor,
                                                      int* __restrict__ ssrc,
                                                      float* __restrict__ sea) {
  int t = blockIdx.x * 256 + threadIdx.x;
  float mean = esum[0] * (1.0f / NE);
  for (int e = t; e < EP; e += gridDim.x * 256) {
    int src, dst;
    float v;
    if (e < NE) {
      src = ei[e];
      dst = ei[NE + e];
      v = ea[e];
    } else {
      src = dst = e - NE;
      v = mean;
    }
    int pos = atomicAdd(&cursor[dst], 1);
    ssrc[pos] = src;
    sea[pos] = v;
  }
}

// ================= fused GATv2 edge phase =================
// One wave per dst node. Lane l owns elements l*4..l*4+3 (all in head l>>4).
// Per edge in the dst bucket: logits via 16-lane shfl reduce, online softmax
// (flash-style), weighted accumulation of xl[src]. Epilogue: /den + bias, relu.
__global__ __launch_bounds__(256) void gat_fused_kernel(const int* __restrict__ offsets,
                                                        const int* __restrict__ counts,
                                                        const int* __restrict__ ssrc,
                                                        const float* __restrict__ sea,
                                                        const float* __restrict__ xl,
                                                        const float* __restrict__ xr,
                                                        const float* __restrict__ we,
                                                        const float* __restrict__ att,
                                                        const float* __restrict__ bias,
                                                        float* __restrict__ h) {
  int w = threadIdx.x >> 6, lane = threadIdx.x & 63;
  int d = blockIdx.x * 4 + w;
  if (d >= NN) return;
  int off = offsets[d], cnt = counts[d];
  const int c4 = lane * 4;
  const float4 xr4 = *(const float4*)(xr + (size_t)d * 256 + c4);
  const float4 we4 = *(const float4*)(we + c4);
  const float4 at4 = *(const float4*)(att + c4);
  float4 acc = {0.f, 0.f, 0.f, 0.f};
  float den = 0.f, m = -1e30f;
  for (int i = 0; i < cnt; i++) {
    int src = ssrc[off + i];
    float eav = sea[off + i];
    float4 x4 = *(const float4*)(xl + (size_t)src * 256 + c4);
    float v0 = x4.x + xr4.x + eav * we4.x;
    float v1 = x4.y + xr4.y + eav * we4.y;
    float v2 = x4.z + xr4.z + eav * we4.z;
    float v3 = x4.w + xr4.w + eav * we4.w;
    v0 = v0 > 0.f ? v0 : NEG * v0;
    v1 = v1 > 0.f ? v1 : NEG * v1;
    v2 = v2 > 0.f ? v2 : NEG * v2;
    v3 = v3 > 0.f ? v3 : NEG * v3;
    float p = v0 * at4.x + v1 * at4.y + v2 * at4.z + v3 * at4.w;
    p += __shfl_xor(p, 1, 64);
    p += __shfl_xor(p, 2, 64);
    p += __shfl_xor(p, 4, 64);
    p += __shfl_xor(p, 8, 64);  // p = logit for head (lane>>4)
    float mn = fmaxf(m, p);
    float sc = __expf(m - mn);
    float ex = __expf(p - mn);
    den = den * sc + ex;
    acc.x = acc.x * sc + x4.x * ex;
    acc.y = acc.y * sc + x4.y * ex;
    acc.z = acc.z * sc + x4.z * ex;
    acc.w = acc.w * sc + x4.w * ex;
    m = mn;
  }
  const float4 b4 = *(const float4*)(bias + c4);
  float inv = 1.f / den;  // every node has a self-loop -> den > 0
  float4 o;
  o.x = fmaxf(acc.x * inv + b4.x, 0.f);
  o.y = fmaxf(acc.y * inv + b4.y, 0.f);
  o.z = fmaxf(acc.z * inv + b4.z, 0.f);
  o.w = fmaxf(acc.w * inv + b4.w, 0.f);
  *(float4*)(h + (size_t)d * 256 + c4) = o;
}

// ---------- global mean pool (batch is sorted; run-length flush) ----------
__global__ __launch_bounds__(256) void pool_kernel(const float* __restrict__ h,
                                                   const int* __restrict__ batch,
                                                   float* __restrict__ sums,
                                                   float* __restrict__ cnts) {
  __shared__ int sb[128];
  int n0 = blockIdx.x * 128;
  int j = threadIdx.x;
  int count = min(128, NN - n0);
  if (count <= 0) return;
  for (int t = threadIdx.x; t < count; t += 256) sb[t] = batch[n0 + t];
  __syncthreads();
  float acc = 0.f;
  int run = 0;
  int cur = sb[0];
  for (int i = 0; i < count; ++i) {
    int b = sb[i];
    if (b != cur) {
      atomicAdd(&sums[(size_t)cur * 256 + j], acc);
      if (j == 0) atomicAdd(&cnts[cur], (float)run);
      acc = 0.f;
      run = 0;
      cur = b;
    }
    acc += h[(size_t)(n0 + i) * 256 + j];
    run++;
  }
  atomicAdd(&sums[(size_t)cur * 256 + j], acc);
  if (j == 0) atomicAdd(&cnts[cur], (float)run);
}

// ---------- post-MLP head: one block per graph ----------
__global__ __launch_bounds__(128) void head_kernel(const float* __restrict__ sums,
                                                   const float* __restrict__ cnts,
                                                   const float* __restrict__ p1_w,
                                                   const float* __restrict__ p1_b,
                                                   const float* __restrict__ ln_g,
                                                   const float* __restrict__ ln_b,
                                                   const float* __restrict__ p2_w,
                                                   const float* __restrict__ p2_b,
                                                   const float* __restrict__ hc_w,
                                                   const float* __restrict__ hc_b,
                                                   const float* __restrict__ hf_w,
                                                   const float* __restrict__ hf_b,
                                                   float* __restrict__ out) {
  int g = blockIdx.x;
  int j = threadIdx.x;  // 0..127
  __shared__ float sp[256], st[128], sz[64];
  float cnt = fmaxf(cnts[g], 1.0f);
  for (int t = j; t < 256; t += 128) sp[t] = sums[(size_t)g * 256 + t] / cnt;
  __syncthreads();
  float acc = p1_b[j];
  for (int k = 0; k < 256; k++) acc += sp[k] * p1_w[(size_t)k * 128 + j];
  st[j] = acc;
  __syncthreads();
  float mu = 0.f;
  for (int k = 0; k < 128; k++) mu += st[k];
  mu *= (1.f / 128.f);
  float var = 0.f;
  for (int k = 0; k < 128; k++) {
    float d = st[k] - mu;
    var += d * d;
  }
  var *= (1.f / 128.f);
  float tj = (acc - mu) * rsqrtf(var + 1e-5f) * ln_g[j] + ln_b[j];
  tj = fmaxf(tj, 0.f);
  __syncthreads();
  st[j] = tj;
  __syncthreads();
  if (j < 64) {
    float z = p2_b[j];
    for (int k = 0; k < 128; k++) z += st[k] * p2_w[(size_t)k * 64 + j];
    z = fmaxf(z, 0.f);
    sz[j] = z;
    out[500 + (size_t)g * 64 + j] = z;  // output 2: z [B,64]
  }
  __syncthreads();
  if (j == 0) {
    float c = hc_b[0];
    for (int k = 0; k < 64; k++) c += sz[k] * hc_w[k];
    out[g] = c;  // output 0: cooling [B]
  }
  if (j >= 1 && j < 10) {
    int f = j - 1;
    float v = hf_b[f];
    for (int k = 0; k < 64; k++) v += sz[k] * hf_w[(size_t)k * 9 + f];
    out[50 + (size_t)g * 9 + f] = v;  // output 1: fatigue [B,9]
  }
}

extern "C" void kernel_launch(void* const* d_in, const int* in_sizes, int n_in,
                              void* d_out, int out_size, void* d_ws, size_t ws_size,
                              hipStream_t stream) {
  const float* x = (const float*)d_in[0];
  const int* ei = (const int*)d_in[1];
  const float* ea = (const float*)d_in[2];
  const int* batch = (const int*)d_in[3];
  const float* enc_w = (const float*)d_in[4];
  const float* enc_b = (const float*)d_in[5];
  const float* g1_wl = (const float*)d_in[6];
  const float* g1_bl = (const float*)d_in[7];
  const float* g1_wr = (const float*)d_in[8];
  const float* g1_br = (const float*)d_in[9];
  const float* g1_we = (const float*)d_in[10];
  const float* g1_att = (const float*)d_in[11];
  const float* g1_bias = (const float*)d_in[12];
  const float* g2_wl = (const float*)d_in[13];
  const float* g2_bl = (const float*)d_in[14];
  const float* g2_wr = (const float*)d_in[15];
  const float* g2_br = (const float*)d_in[16];
  const float* g2_we = (const float*)d_in[17];
  const float* g2_att = (const float*)d_in[18];
  const float* g2_bias = (const float*)d_in[19];
  const float* p1_w = (const float*)d_in[20];
  const float* p1_b = (const float*)d_in[21];
  const float* ln_g = (const float*)d_in[22];
  const float* ln_b = (const float*)d_in[23];
  const float* p2_w = (const float*)d_in[24];
  const float* p2_b = (const float*)d_in[25];
  const float* hc_w = (const float*)d_in[26];
  const float* hc_b = (const float*)d_in[27];
  const float* hf_w = (const float*)d_in[28];
  const float* hf_b = (const float*)d_in[29];
  float* out = (float*)d_out;

  // ---- workspace layout ----
  float* ws = (float*)d_ws;
  float* buf1 = ws;                       // N*256 (h0 in first N*64, then h)
  float* xl = buf1 + (size_t)NN * 256;    // N*256
  float* xr = xl + (size_t)NN * 256;      // N*256
  float* sea = xr + (size_t)NN * 256;     // EP
  int* ssrc = (int*)(sea + EP);           // EP
  int* counts = ssrc + EP;                // NN
  int* offsets = counts + NN;             // NN
  int* cursor = offsets + NN;             // NN
  int* bsum = cursor + NN;                // NBLK_SCAN
  float* sums = (float*)(bsum + NBLK_SCAN);  // B*256
  float* cnts = sums + (size_t)NB * 256;     // B
  float* esum = cnts + NB;                   // 1

  // ---- edge_attr mean ----
  hipMemsetAsync(esum, 0, sizeof(float), stream);
  reduce_sum_kernel<<<256, 256, 0, stream>>>(ea, esum);

  // ---- counting sort of edges by dst (graph is static: reused by both layers) ----
  hipMemsetAsync(counts, 0, (size_t)NN * sizeof(int), stream);
  hist_kernel<<<1024, 256, 0, stream>>>(ei, counts);
  scanA_kernel<<<NBLK_SCAN, 256, 0, stream>>>(counts, bsum);
  scanB_kernel<<<1, 64, 0, stream>>>(bsum);
  scanC_kernel<<<NBLK_SCAN, 256, 0, stream>>>(counts, bsum, offsets, cursor);
  scatter_kernel<<<1024, 256, 0, stream>>>(ei, ea, esum, cursor, ssrc, sea);

  // ---- encoder ----
  encoder_kernel<<<(NN * 64 + 255) / 256, 256, 0, stream>>>(x, enc_w, enc_b, buf1);

  // ================= GAT layer 1 (K=64) =================
  linear_kernel<<<NN / 16, 256, 0, stream>>>(buf1, 64, g1_wl, g1_bl, xl);
  linear_kernel<<<NN / 16, 256, 0, stream>>>(buf1, 64, g1_wr, g1_br, xr);
  gat_fused_kernel<<<(NN + 3) / 4, 256, 0, stream>>>(offsets, counts, ssrc, sea, xl, xr,
                                                     g1_we, g1_att, g1_bias, buf1);

  // ================= GAT layer 2 (K=256) =================
  linear_kernel<<<NN / 16, 256, 0, stream>>>(buf1, 256, g2_wl, g2_bl, xl);
  linear_kernel<<<NN / 16, 256, 0, stream>>>(buf1, 256, g2_wr, g2_br, xr);
  gat_fused_kernel<<<(NN + 3) / 4, 256, 0, stream>>>(offsets, counts, ssrc, sea, xl, xr,
                                                     g2_we, g2_att, g2_bias, buf1);

  // ================= pool + head =================
  hipMemsetAsync(sums, 0, (size_t)NB * 256 * sizeof(float), stream);
  hipMemsetAsync(cnts, 0, (size_t)NB * sizeof(float), stream);
  pool_kernel<<<(NN + 127) / 128, 256, 0, stream>>>(buf1, batch, sums, cnts);
  head_kernel<<<NB, 128, 0, stream>>>(sums, cnts, p1_w, p1_b, ln_g, ln_b, p2_w, p2_b,
                                      hc_w, hc_b, hf_w, hf_b, out);
}

// Round 3
// 481.123 us; speedup vs baseline: 4.4510x; 1.8490x over previous
//
#include <hip/hip_runtime.h>
#include <hip/hip_bf16.h>

#define NN 50000      // nodes
#define NE 500000     // edges (without self loops)
#define EP (NE + NN)  // edges with self loops
#define NB 50         // graphs
#define NEG 0.2f
#define NBLK_SCAN 196  // ceil(NN/256)

typedef __attribute__((ext_vector_type(8))) short short8;
typedef __attribute__((ext_vector_type(4))) float f32x4;

__device__ __forceinline__ ushort f2bf(float f) {
  unsigned u = __float_as_uint(f);
  unsigned r = (u + 0x7FFFu + ((u >> 16) & 1u)) >> 16;
  return (ushort)r;
}
__device__ __forceinline__ float bf2f(ushort b) {
  return __uint_as_float(((unsigned)b) << 16);
}

// ---------- mean(edge_attr) : sum into esum[0] ----------
__global__ __launch_bounds__(256) void reduce_sum_kernel(const float* __restrict__ ea,
                                                         float* __restrict__ esum) {
  int t = blockIdx.x * 256 + threadIdx.x;
  float v = 0.f;
  for (int i = t; i < NE; i += gridDim.x * 256) v += ea[i];
  for (int off = 1; off < 64; off <<= 1) v += __shfl_xor(v, off, 64);
  if ((threadIdx.x & 63) == 0) atomicAdd(esum, v);
}

// ---------- weight convert+transpose: W[K][256] f32 -> Wt[256][K] bf16 ----------
__global__ __launch_bounds__(256) void wconv_kernel(const float* __restrict__ W,
                                                    int kshift,  // log2(K)
                                                    ushort* __restrict__ Wt) {
  int K = 1 << kshift;
  int t = blockIdx.x * 256 + threadIdx.x;
  if (t >= (K << 8)) return;
  int n = t >> kshift;
  int k = t & (K - 1);
  Wt[t] = f2bf(W[(size_t)k * 256 + n]);
}

// ---------- encoder: h0[n][j] = relu(x[n,:8] @ enc_w + enc_b), bf16 out ----------
__global__ __launch_bounds__(256) void encoder_kernel(const float* __restrict__ x,
                                                      const float* __restrict__ w,
                                                      const float* __restrict__ b,
                                                      ushort* __restrict__ h0) {
  int t = blockIdx.x * 256 + threadIdx.x;
  if (t >= NN * 64) return;
  int n = t >> 6, j = t & 63;
  float acc = b[j];
#pragma unroll
  for (int k = 0; k < 8; k++) acc += x[n * 8 + k] * w[k * 64 + j];
  h0[t] = f2bf(fmaxf(acc, 0.f));
}

// ---------- fused dual linear via MFMA: xl = A@Wl^T+bl ; xr = A@Wr^T+br ----------
// A: [NN][K] bf16. Wl/Wr: [256][K] bf16 (pre-transposed). Outputs f32 [NN][256].
// Block: 256 thr = 4 waves. BM=32 rows/block. Waves 0,1 -> Wl cols 0..255;
// waves 2,3 -> Wr. Per wave: 2x8 fragments of 16x16 (cols wave&1 ? 128..255 : 0..127).
__global__ __launch_bounds__(256) void dual_linear_mfma(const ushort* __restrict__ A, int K,
                                                        const ushort* __restrict__ Wl,
                                                        const ushort* __restrict__ Wr,
                                                        const float* __restrict__ bl,
                                                        const float* __restrict__ br,
                                                        float* __restrict__ xl,
                                                        float* __restrict__ xr) {
  int wave = threadIdx.x >> 6, lane = threadIdx.x & 63;
  int r0 = blockIdx.x * 32;
  int lr = lane & 15;        // row-in-frag (A) / col-in-frag (B/D)
  int kb = (lane >> 4) * 8;  // k-base within 32-wide k-step
  const ushort* W = (wave < 2) ? Wl : Wr;
  int wc0 = (wave & 1) * 128;
  f32x4 acc[2][8];
#pragma unroll
  for (int fr = 0; fr < 2; fr++)
#pragma unroll
    for (int fc = 0; fc < 8; fc++) acc[fr][fc] = (f32x4){0.f, 0.f, 0.f, 0.f};
  int rowA0 = min(r0 + 0 * 16 + lr, NN - 1);
  int rowA1 = min(r0 + 1 * 16 + lr, NN - 1);
  const ushort* pa0 = A + (size_t)rowA0 * K + kb;
  const ushort* pa1 = A + (size_t)rowA1 * K + kb;
  const ushort* pb = W + (size_t)(wc0 + lr) * K + kb;
  for (int k0 = 0; k0 < K; k0 += 32) {
    short8 a0 = *(const short8*)(pa0 + k0);
    short8 a1 = *(const short8*)(pa1 + k0);
    short8 b[8];
#pragma unroll
    for (int fc = 0; fc < 8; fc++) b[fc] = *(const short8*)(pb + (size_t)fc * 16 * K + k0);
#pragma unroll
    for (int fc = 0; fc < 8; fc++) {
      acc[0][fc] = __builtin_amdgcn_mfma_f32_16x16x32_bf16(a0, b[fc], acc[0][fc], 0, 0, 0);
      acc[1][fc] = __builtin_amdgcn_mfma_f32_16x16x32_bf16(a1, b[fc], acc[1][fc], 0, 0, 0);
    }
  }
  const float* bias = (wave < 2) ? bl : br;
  float* O = (wave < 2) ? xl : xr;
#pragma unroll
  for (int fc = 0; fc < 8; fc++) {
    int c = wc0 + fc * 16 + lr;
    float bv = bias[c];
#pragma unroll
    for (int fr = 0; fr < 2; fr++) {
#pragma unroll
      for (int j = 0; j < 4; j++) {
        int row = r0 + fr * 16 + (lane >> 4) * 4 + j;
        if (row < NN) O[(size_t)row * 256 + c] = acc[fr][fc][j] + bv;
      }
    }
  }
}

// ================= counting sort of edges by dst =================
__global__ __launch_bounds__(256) void hist_kernel(const int* __restrict__ ei,
                                                   int* __restrict__ counts) {
  int t = blockIdx.x * 256 + threadIdx.x;
  for (int e = t; e < EP; e += gridDim.x * 256) {
    int dst = (e < NE) ? ei[NE + e] : e - NE;
    atomicAdd(&counts[dst], 1);
  }
}

__global__ __launch_bounds__(256) void scanA_kernel(const int* __restrict__ counts,
                                                    int* __restrict__ bsum) {
  int i = blockIdx.x * 256 + threadIdx.x;
  int v = (i < NN) ? counts[i] : 0;
  for (int off = 1; off < 64; off <<= 1) v += __shfl_xor(v, off, 64);
  __shared__ int sw[4];
  if ((threadIdx.x & 63) == 0) sw[threadIdx.x >> 6] = v;
  __syncthreads();
  if (threadIdx.x == 0) bsum[blockIdx.x] = sw[0] + sw[1] + sw[2] + sw[3];
}

__global__ void scanB_kernel(int* __restrict__ bsum) {
  if (threadIdx.x == 0 && blockIdx.x == 0) {
    int run = 0;
    for (int b = 0; b < NBLK_SCAN; b++) {
      int v = bsum[b];
      bsum[b] = run;
      run += v;
    }
  }
}

__global__ __launch_bounds__(256) void scanC_kernel(const int* __restrict__ counts,
                                                    const int* __restrict__ bpre,
                                                    int* __restrict__ offsets,
                                                    int* __restrict__ cursor) {
  __shared__ int s[256];
  int i = blockIdx.x * 256 + threadIdx.x;
  int v = (i < NN) ? counts[i] : 0;
  s[threadIdx.x] = v;
  __syncthreads();
  for (int off = 1; off < 256; off <<= 1) {
    int add = (threadIdx.x >= off) ? s[threadIdx.x - off] : 0;
    __syncthreads();
    s[threadIdx.x] += add;
    __syncthreads();
  }
  if (i < NN) {
    int excl = s[threadIdx.x] - v + bpre[blockIdx.x];
    offsets[i] = excl;
    cursor[i] = excl;
  }
}

__global__ __launch_bounds__(256) void scatter_kernel(const int* __restrict__ ei,
                                                      const float* __restrict__ ea,
                                                      const float* __restrict__ esum,
                                                      int* __restrict__ cursor,
                                                      int* __restrict__ ssrc,
                                                      float* __restrict__ sea) {
  int t = blockIdx.x * 256 + threadIdx.x;
  float mean = esum[0] * (1.0f / NE);
  for (int e = t; e < EP; e += gridDim.x * 256) {
    int src, dst;
    float v;
    if (e < NE) {
      src = ei[e];
      dst = ei[NE + e];
      v = ea[e];
    } else {
      src = dst = e - NE;
      v = mean;
    }
    int pos = atomicAdd(&cursor[dst], 1);
    ssrc[pos] = src;
    sea[pos] = v;
  }
}

// ================= fused GATv2 edge phase (gather form) =================
// One wave per dst node; lane l owns elements l*4..l*4+3 (head l>>4).
// Online softmax + weighted aggregation, epilogue /den + bias + relu -> bf16.
__global__ __launch_bounds__(256) void gat_fused_kernel(const int* __restrict__ offsets,
                                                        const int* __restrict__ counts,
                                                        const int* __restrict__ ssrc,
                                                        const float* __restrict__ sea,
                                                        const float* __restrict__ xl,
                                                        const float* __restrict__ xr,
                                                        const float* __restrict__ we,
                                                        const float* __restrict__ att,
                                                        const float* __restrict__ bias,
                                                        ushort* __restrict__ hb) {
  int w = threadIdx.x >> 6, lane = threadIdx.x & 63;
  int d = blockIdx.x * 4 + w;
  if (d >= NN) return;
  int off = offsets[d], cnt = counts[d];
  const int c4 = lane * 4;
  const float4 xr4 = *(const float4*)(xr + (size_t)d * 256 + c4);
  const float4 we4 = *(const float4*)(we + c4);
  const float4 at4 = *(const float4*)(att + c4);
  float4 acc = {0.f, 0.f, 0.f, 0.f};
  float den = 0.f, m = -1e30f;
  for (int i = 0; i < cnt; i++) {
    int src = ssrc[off + i];
    float eav = sea[off + i];
    float4 x4 = *(const float4*)(xl + (size_t)src * 256 + c4);
    float v0 = x4.x + xr4.x + eav * we4.x;
    float v1 = x4.y + xr4.y + eav * we4.y;
    float v2 = x4.z + xr4.z + eav * we4.z;
    float v3 = x4.w + xr4.w + eav * we4.w;
    v0 = v0 > 0.f ? v0 : NEG * v0;
    v1 = v1 > 0.f ? v1 : NEG * v1;
    v2 = v2 > 0.f ? v2 : NEG * v2;
    v3 = v3 > 0.f ? v3 : NEG * v3;
    float p = v0 * at4.x + v1 * at4.y + v2 * at4.z + v3 * at4.w;
    p += __shfl_xor(p, 1, 64);
    p += __shfl_xor(p, 2, 64);
    p += __shfl_xor(p, 4, 64);
    p += __shfl_xor(p, 8, 64);  // p = logit for head (lane>>4)
    float mn = fmaxf(m, p);
    float sc = __expf(m - mn);
    float ex = __expf(p - mn);
    den = den * sc + ex;
    acc.x = acc.x * sc + x4.x * ex;
    acc.y = acc.y * sc + x4.y * ex;
    acc.z = acc.z * sc + x4.z * ex;
    acc.w = acc.w * sc + x4.w * ex;
    m = mn;
  }
  const float4 b4 = *(const float4*)(bias + c4);
  float inv = 1.f / den;  // every node has a self-loop -> den > 0
  ushort4 o;
  o.x = f2bf(fmaxf(acc.x * inv + b4.x, 0.f));
  o.y = f2bf(fmaxf(acc.y * inv + b4.y, 0.f));
  o.z = f2bf(fmaxf(acc.z * inv + b4.z, 0.f));
  o.w = f2bf(fmaxf(acc.w * inv + b4.w, 0.f));
  *(ushort4*)(hb + (size_t)d * 256 + c4) = o;
}

// ---------- global mean pool (batch is sorted; run-length flush) ----------
__global__ __launch_bounds__(256) void pool_kernel(const ushort* __restrict__ h,
                                                   const int* __restrict__ batch,
                                                   float* __restrict__ sums,
                                                   float* __restrict__ cnts) {
  __shared__ int sb[128];
  int n0 = blockIdx.x * 128;
  int j = threadIdx.x;
  int count = min(128, NN - n0);
  if (count <= 0) return;
  for (int t = threadIdx.x; t < count; t += 256) sb[t] = batch[n0 + t];
  __syncthreads();
  float acc = 0.f;
  int run = 0;
  int cur = sb[0];
  for (int i = 0; i < count; ++i) {
    int b = sb[i];
    if (b != cur) {
      atomicAdd(&sums[(size_t)cur * 256 + j], acc);
      if (j == 0) atomicAdd(&cnts[cur], (float)run);
      acc = 0.f;
      run = 0;
      cur = b;
    }
    acc += bf2f(h[(size_t)(n0 + i) * 256 + j]);
    run++;
  }
  atomicAdd(&sums[(size_t)cur * 256 + j], acc);
  if (j == 0) atomicAdd(&cnts[cur], (float)run);
}

// ---------- post-MLP head: one block per graph ----------
__global__ __launch_bounds__(128) void head_kernel(const float* __restrict__ sums,
                                                   const float* __restrict__ cnts,
                                                   const float* __restrict__ p1_w,
                                                   const float* __restrict__ p1_b,
                                                   const float* __restrict__ ln_g,
                                                   const float* __restrict__ ln_b,
                                                   const float* __restrict__ p2_w,
                                                   const float* __restrict__ p2_b,
                                                   const float* __restrict__ hc_w,
                                                   const float* __restrict__ hc_b,
                                                   const float* __restrict__ hf_w,
                                                   const float* __restrict__ hf_b,
                                                   float* __restrict__ out) {
  int g = blockIdx.x;
  int j = threadIdx.x;  // 0..127
  __shared__ float sp[256], st[128], sz[64];
  float cnt = fmaxf(cnts[g], 1.0f);
  for (int t = j; t < 256; t += 128) sp[t] = sums[(size_t)g * 256 + t] / cnt;
  __syncthreads();
  float acc = p1_b[j];
  for (int k = 0; k < 256; k++) acc += sp[k] * p1_w[(size_t)k * 128 + j];
  st[j] = acc;
  __syncthreads();
  float mu = 0.f;
  for (int k = 0; k < 128; k++) mu += st[k];
  mu *= (1.f / 128.f);
  float var = 0.f;
  for (int k = 0; k < 128; k++) {
    float d = st[k] - mu;
    var += d * d;
  }
  var *= (1.f / 128.f);
  float tj = (acc - mu) * rsqrtf(var + 1e-5f) * ln_g[j] + ln_b[j];
  tj = fmaxf(tj, 0.f);
  __syncthreads();
  st[j] = tj;
  __syncthreads();
  if (j < 64) {
    float z = p2_b[j];
    for (int k = 0; k < 128; k++) z += st[k] * p2_w[(size_t)k * 64 + j];
    z = fmaxf(z, 0.f);
    sz[j] = z;
    out[500 + (size_t)g * 64 + j] = z;  // output 2: z [B,64]
  }
  __syncthreads();
  if (j == 0) {
    float c = hc_b[0];
    for (int k = 0; k < 64; k++) c += sz[k] * hc_w[k];
    out[g] = c;  // output 0: cooling [B]
  }
  if (j >= 1 && j < 10) {
    int f = j - 1;
    float v = hf_b[f];
    for (int k = 0; k < 64; k++) v += sz[k] * hf_w[(size_t)k * 9 + f];
    out[50 + (size_t)g * 9 + f] = v;  // output 1: fatigue [B,9]
  }
}

extern "C" void kernel_launch(void* const* d_in, const int* in_sizes, int n_in,
                              void* d_out, int out_size, void* d_ws, size_t ws_size,
                              hipStream_t stream) {
  const float* x = (const float*)d_in[0];
  const int* ei = (const int*)d_in[1];
  const float* ea = (const float*)d_in[2];
  const int* batch = (const int*)d_in[3];
  const float* enc_w = (const float*)d_in[4];
  const float* enc_b = (const float*)d_in[5];
  const float* g1_wl = (const float*)d_in[6];
  const float* g1_bl = (const float*)d_in[7];
  const float* g1_wr = (const float*)d_in[8];
  const float* g1_br = (const float*)d_in[9];
  const float* g1_we = (const float*)d_in[10];
  const float* g1_att = (const float*)d_in[11];
  const float* g1_bias = (const float*)d_in[12];
  const float* g2_wl = (const float*)d_in[13];
  const float* g2_bl = (const float*)d_in[14];
  const float* g2_wr = (const float*)d_in[15];
  const float* g2_br = (const float*)d_in[16];
  const float* g2_we = (const float*)d_in[17];
  const float* g2_att = (const float*)d_in[18];
  const float* g2_bias = (const float*)d_in[19];
  const float* p1_w = (const float*)d_in[20];
  const float* p1_b = (const float*)d_in[21];
  const float* ln_g = (const float*)d_in[22];
  const float* ln_b = (const float*)d_in[23];
  const float* p2_w = (const float*)d_in[24];
  const float* p2_b = (const float*)d_in[25];
  const float* hc_w = (const float*)d_in[26];
  const float* hc_b = (const float*)d_in[27];
  const float* hf_w = (const float*)d_in[28];
  const float* hf_b = (const float*)d_in[29];
  float* out = (float*)d_out;

  // ---- workspace layout ----
  float* ws = (float*)d_ws;
  float* xl = ws;                            // N*256 f32
  float* xr = xl + (size_t)NN * 256;         // N*256 f32
  ushort* hb = (ushort*)(xr + (size_t)NN * 256);  // N*256 bf16
  ushort* h0b = hb + (size_t)NN * 256;       // N*64 bf16
  ushort* w1l = h0b + (size_t)NN * 64;       // 256*64 bf16 (transposed)
  ushort* w1r = w1l + 256 * 64;
  ushort* w2l = w1r + 256 * 64;              // 256*256 bf16
  ushort* w2r = w2l + 256 * 256;
  float* sea = (float*)(w2r + 256 * 256);    // EP
  int* ssrc = (int*)(sea + EP);              // EP
  int* counts = ssrc + EP;                   // NN
  int* offsets = counts + NN;                // NN
  int* cursor = offsets + NN;                // NN
  int* bsum = cursor + NN;                   // NBLK_SCAN
  float* sums = (float*)(bsum + NBLK_SCAN);  // B*256
  float* cnts = sums + (size_t)NB * 256;     // B
  float* esum = cnts + NB;                   // 1

  // ---- edge_attr mean ----
  hipMemsetAsync(esum, 0, sizeof(float), stream);
  reduce_sum_kernel<<<256, 256, 0, stream>>>(ea, esum);

  // ---- counting sort of edges by dst (graph static: reused by both layers) ----
  hipMemsetAsync(counts, 0, (size_t)NN * sizeof(int), stream);
  hist_kernel<<<1024, 256, 0, stream>>>(ei, counts);
  scanA_kernel<<<NBLK_SCAN, 256, 0, stream>>>(counts, bsum);
  scanB_kernel<<<1, 64, 0, stream>>>(bsum);
  scanC_kernel<<<NBLK_SCAN, 256, 0, stream>>>(counts, bsum, offsets, cursor);
  scatter_kernel<<<1024, 256, 0, stream>>>(ei, ea, esum, cursor, ssrc, sea);

  // ---- weight conversion (f32 [K][256] -> bf16 [256][K]) ----
  wconv_kernel<<<64, 256, 0, stream>>>(g1_wl, 6, w1l);
  wconv_kernel<<<64, 256, 0, stream>>>(g1_wr, 6, w1r);
  wconv_kernel<<<256, 256, 0, stream>>>(g2_wl, 8, w2l);
  wconv_kernel<<<256, 256, 0, stream>>>(g2_wr, 8, w2r);

  // ---- encoder ----
  encoder_kernel<<<(NN * 64 + 255) / 256, 256, 0, stream>>>(x, enc_w, enc_b, h0b);

  const int nGemmBlocks = (NN + 31) / 32;
  const int nGatBlocks = (NN + 3) / 4;

  // ================= GAT layer 1 (K=64) =================
  dual_linear_mfma<<<nGemmBlocks, 256, 0, stream>>>(h0b, 64, w1l, w1r, g1_bl, g1_br, xl, xr);
  gat_fused_kernel<<<nGatBlocks, 256, 0, stream>>>(offsets, counts, ssrc, sea, xl, xr,
                                                   g1_we, g1_att, g1_bias, hb);

  // ================= GAT layer 2 (K=256) =================
  dual_linear_mfma<<<nGemmBlocks, 256, 0, stream>>>(hb, 256, w2l, w2r, g2_bl, g2_br, xl, xr);
  gat_fused_kernel<<<nGatBlocks, 256, 0, stream>>>(offsets, counts, ssrc, sea, xl, xr,
                                                   g2_we, g2_att, g2_bias, hb);

  // ================= pool + head =================
  hipMemsetAsync(sums, 0, (size_t)NB * 256 * sizeof(float), stream);
  hipMemsetAsync(cnts, 0, (size_t)NB * sizeof(float), stream);
  pool_kernel<<<(NN + 127) / 128, 256, 0, stream>>>(hb, batch, sums, cnts);
  head_kernel<<<NB, 128, 0, stream>>>(sums, cnts, p1_w, p1_b, ln_g, ln_b, p2_w, p2_b,
                                      hc_w, hc_b, hf_w, hf_b, out);
}

// Round 4
// 472.431 us; speedup vs baseline: 4.5329x; 1.0184x over previous
//
#include <hip/hip_runtime.h>
#include <hip/hip_bf16.h>

#define NN 50000      // nodes
#define NE 500000     // edges (without self loops)
#define EP (NE + NN)  // edges with self loops
#define NB 50         // graphs
#define NEG 0.2f
#define NBLK_SCAN 196  // ceil(NN/256)

typedef __attribute__((ext_vector_type(8))) short short8;
typedef __attribute__((ext_vector_type(4))) float f32x4;

__device__ __forceinline__ ushort f2bf(float f) {
  unsigned u = __float_as_uint(f);
  unsigned r = (u + 0x7FFFu + ((u >> 16) & 1u)) >> 16;
  return (ushort)r;
}
__device__ __forceinline__ float bf2f(ushort b) {
  return __uint_as_float(((unsigned)b) << 16);
}

// ---------- mean(edge_attr) : sum into esum[0] ----------
__global__ __launch_bounds__(256) void reduce_sum_kernel(const float* __restrict__ ea,
                                                         float* __restrict__ esum) {
  int t = blockIdx.x * 256 + threadIdx.x;
  float v = 0.f;
  for (int i = t; i < NE; i += gridDim.x * 256) v += ea[i];
  for (int off = 1; off < 64; off <<= 1) v += __shfl_xor(v, off, 64);
  if ((threadIdx.x & 63) == 0) atomicAdd(esum, v);
}

// ---------- weight convert+transpose: W[K][256] f32 -> Wt[256][K] bf16 ----------
__global__ __launch_bounds__(256) void wconv_kernel(const float* __restrict__ W,
                                                    int kshift,  // log2(K)
                                                    ushort* __restrict__ Wt) {
  int K = 1 << kshift;
  int t = blockIdx.x * 256 + threadIdx.x;
  if (t >= (K << 8)) return;
  int n = t >> kshift;
  int k = t & (K - 1);
  Wt[t] = f2bf(W[(size_t)k * 256 + n]);
}

// ---------- encoder: h0[n][j] = relu(x[n,:8] @ enc_w + enc_b), bf16 out ----------
__global__ __launch_bounds__(256) void encoder_kernel(const float* __restrict__ x,
                                                      const float* __restrict__ w,
                                                      const float* __restrict__ b,
                                                      ushort* __restrict__ h0) {
  int t = blockIdx.x * 256 + threadIdx.x;
  if (t >= NN * 64) return;
  int n = t >> 6, j = t & 63;
  float acc = b[j];
#pragma unroll
  for (int k = 0; k < 8; k++) acc += x[n * 8 + k] * w[k * 64 + j];
  h0[t] = f2bf(fmaxf(acc, 0.f));
}

// ---------- fused dual linear via MFMA: xl = A@Wl^T+bl ; xr = A@Wr^T+br ----------
// A: [NN][K] bf16. Wl/Wr: [256][K] bf16 (pre-transposed). Outputs bf16 [NN][256].
__global__ __launch_bounds__(256) void dual_linear_mfma(const ushort* __restrict__ A, int K,
                                                        const ushort* __restrict__ Wl,
                                                        const ushort* __restrict__ Wr,
                                                        const float* __restrict__ bl,
                                                        const float* __restrict__ br,
                                                        ushort* __restrict__ xl,
                                                        ushort* __restrict__ xr) {
  int wave = threadIdx.x >> 6, lane = threadIdx.x & 63;
  int r0 = blockIdx.x * 32;
  int lr = lane & 15;        // row-in-frag (A) / col-in-frag (B/D)
  int kb = (lane >> 4) * 8;  // k-base within 32-wide k-step
  const ushort* W = (wave < 2) ? Wl : Wr;
  int wc0 = (wave & 1) * 128;
  f32x4 acc[2][8];
#pragma unroll
  for (int fr = 0; fr < 2; fr++)
#pragma unroll
    for (int fc = 0; fc < 8; fc++) acc[fr][fc] = (f32x4){0.f, 0.f, 0.f, 0.f};
  int rowA0 = min(r0 + 0 * 16 + lr, NN - 1);
  int rowA1 = min(r0 + 1 * 16 + lr, NN - 1);
  const ushort* pa0 = A + (size_t)rowA0 * K + kb;
  const ushort* pa1 = A + (size_t)rowA1 * K + kb;
  const ushort* pb = W + (size_t)(wc0 + lr) * K + kb;
  for (int k0 = 0; k0 < K; k0 += 32) {
    short8 a0 = *(const short8*)(pa0 + k0);
    short8 a1 = *(const short8*)(pa1 + k0);
    short8 b[8];
#pragma unroll
    for (int fc = 0; fc < 8; fc++) b[fc] = *(const short8*)(pb + (size_t)fc * 16 * K + k0);
#pragma unroll
    for (int fc = 0; fc < 8; fc++) {
      acc[0][fc] = __builtin_amdgcn_mfma_f32_16x16x32_bf16(a0, b[fc], acc[0][fc], 0, 0, 0);
      acc[1][fc] = __builtin_amdgcn_mfma_f32_16x16x32_bf16(a1, b[fc], acc[1][fc], 0, 0, 0);
    }
  }
  const float* bias = (wave < 2) ? bl : br;
  ushort* O = (wave < 2) ? xl : xr;
#pragma unroll
  for (int fc = 0; fc < 8; fc++) {
    int c = wc0 + fc * 16 + lr;
    float bv = bias[c];
#pragma unroll
    for (int fr = 0; fr < 2; fr++) {
#pragma unroll
      for (int j = 0; j < 4; j++) {
        int row = r0 + fr * 16 + (lane >> 4) * 4 + j;
        if (row < NN) O[(size_t)row * 256 + c] = f2bf(acc[fr][fc][j] + bv);
      }
    }
  }
}

// ================= counting sort of edges by dst =================
__global__ __launch_bounds__(256) void hist_kernel(const int* __restrict__ ei,
                                                   int* __restrict__ counts) {
  int t = blockIdx.x * 256 + threadIdx.x;
  for (int e = t; e < EP; e += gridDim.x * 256) {
    int dst = (e < NE) ? ei[NE + e] : e - NE;
    atomicAdd(&counts[dst], 1);
  }
}

__global__ __launch_bounds__(256) void scanA_kernel(const int* __restrict__ counts,
                                                    int* __restrict__ bsum) {
  int i = blockIdx.x * 256 + threadIdx.x;
  int v = (i < NN) ? counts[i] : 0;
  for (int off = 1; off < 64; off <<= 1) v += __shfl_xor(v, off, 64);
  __shared__ int sw[4];
  if ((threadIdx.x & 63) == 0) sw[threadIdx.x >> 6] = v;
  __syncthreads();
  if (threadIdx.x == 0) bsum[blockIdx.x] = sw[0] + sw[1] + sw[2] + sw[3];
}

__global__ void scanB_kernel(int* __restrict__ bsum) {
  if (threadIdx.x == 0 && blockIdx.x == 0) {
    int run = 0;
    for (int b = 0; b < NBLK_SCAN; b++) {
      int v = bsum[b];
      bsum[b] = run;
      run += v;
    }
  }
}

__global__ __launch_bounds__(256) void scanC_kernel(const int* __restrict__ counts,
                                                    const int* __restrict__ bpre,
                                                    int* __restrict__ offsets,
                                                    int* __restrict__ cursor) {
  __shared__ int s[256];
  int i = blockIdx.x * 256 + threadIdx.x;
  int v = (i < NN) ? counts[i] : 0;
  s[threadIdx.x] = v;
  __syncthreads();
  for (int off = 1; off < 256; off <<= 1) {
    int add = (threadIdx.x >= off) ? s[threadIdx.x - off] : 0;
    __syncthreads();
    s[threadIdx.x] += add;
    __syncthreads();
  }
  if (i < NN) {
    int excl = s[threadIdx.x] - v + bpre[blockIdx.x];
    offsets[i] = excl;
    cursor[i] = excl;
  }
}

__global__ __launch_bounds__(256) void scatter_kernel(const int* __restrict__ ei,
                                                      const float* __restrict__ ea,
                                                      const float* __restrict__ esum,
                                                      int* __restrict__ cursor,
                                                      int* __restrict__ ssrc,
                                                      float* __restrict__ sea) {
  int t = blockIdx.x * 256 + threadIdx.x;
  float mean = esum[0] * (1.0f / NE);
  for (int e = t; e < EP; e += gridDim.x * 256) {
    int src, dst;
    float v;
    if (e < NE) {
      src = ei[e];
      dst = ei[NE + e];
      v = ea[e];
    } else {
      src = dst = e - NE;
      v = mean;
    }
    int pos = atomicAdd(&cursor[dst], 1);
    ssrc[pos] = src;
    sea[pos] = v;
  }
}

// ================= fused GATv2 edge phase (gather form, bf16 xl/xr) =============
// One wave per dst node; lane l owns elements l*4..l*4+3 (head l>>4).
// Online softmax + weighted aggregation; 1-deep software pipeline on the gather.
__global__ __launch_bounds__(256) void gat_fused_kernel(const int* __restrict__ offsets,
                                                        const int* __restrict__ counts,
                                                        const int* __restrict__ ssrc,
                                                        const float* __restrict__ sea,
                                                        const ushort* __restrict__ xl,
                                                        const ushort* __restrict__ xr,
                                                        const float* __restrict__ we,
                                                        const float* __restrict__ att,
                                                        const float* __restrict__ bias,
                                                        ushort* __restrict__ hb) {
  int w = threadIdx.x >> 6, lane = threadIdx.x & 63;
  int d = blockIdx.x * 4 + w;
  if (d >= NN) return;
  int off = offsets[d], cnt = counts[d];
  const int c4 = lane * 4;
  ushort4 xru = *(const ushort4*)(xr + (size_t)d * 256 + c4);
  const float4 xr4 = {bf2f(xru.x), bf2f(xru.y), bf2f(xru.z), bf2f(xru.w)};
  const float4 we4 = *(const float4*)(we + c4);
  const float4 at4 = *(const float4*)(att + c4);
  float4 acc = {0.f, 0.f, 0.f, 0.f};
  float den = 0.f, m = -1e30f;
  // prefetch edge 0
  ushort4 xun = *(const ushort4*)(xl + (size_t)ssrc[off] * 256 + c4);
  float ean = sea[off];
  for (int i = 0; i < cnt; i++) {
    ushort4 xu = xun;
    float eav = ean;
    if (i + 1 < cnt) {  // issue next gather before computing current edge
      int s2 = ssrc[off + i + 1];
      ean = sea[off + i + 1];
      xun = *(const ushort4*)(xl + (size_t)s2 * 256 + c4);
    }
    float4 x4 = {bf2f(xu.x), bf2f(xu.y), bf2f(xu.z), bf2f(xu.w)};
    float v0 = x4.x + xr4.x + eav * we4.x;
    float v1 = x4.y + xr4.y + eav * we4.y;
    float v2 = x4.z + xr4.z + eav * we4.z;
    float v3 = x4.w + xr4.w + eav * we4.w;
    v0 = v0 > 0.f ? v0 : NEG * v0;
    v1 = v1 > 0.f ? v1 : NEG * v1;
    v2 = v2 > 0.f ? v2 : NEG * v2;
    v3 = v3 > 0.f ? v3 : NEG * v3;
    float p = v0 * at4.x + v1 * at4.y + v2 * at4.z + v3 * at4.w;
    p += __shfl_xor(p, 1, 64);
    p += __shfl_xor(p, 2, 64);
    p += __shfl_xor(p, 4, 64);
    p += __shfl_xor(p, 8, 64);  // p = logit for head (lane>>4)
    float mn = fmaxf(m, p);
    float sc = __expf(m - mn);
    float ex = __expf(p - mn);
    den = den * sc + ex;
    acc.x = acc.x * sc + x4.x * ex;
    acc.y = acc.y * sc + x4.y * ex;
    acc.z = acc.z * sc + x4.z * ex;
    acc.w = acc.w * sc + x4.w * ex;
    m = mn;
  }
  const float4 b4 = *(const float4*)(bias + c4);
  float inv = 1.f / den;  // every node has a self-loop -> den > 0
  ushort4 o;
  o.x = f2bf(fmaxf(acc.x * inv + b4.x, 0.f));
  o.y = f2bf(fmaxf(acc.y * inv + b4.y, 0.f));
  o.z = f2bf(fmaxf(acc.z * inv + b4.z, 0.f));
  o.w = f2bf(fmaxf(acc.w * inv + b4.w, 0.f));
  *(ushort4*)(hb + (size_t)d * 256 + c4) = o;
}

// ---------- global mean pool (batch is sorted; run-length flush) ----------
__global__ __launch_bounds__(256) void pool_kernel(const ushort* __restrict__ h,
                                                   const int* __restrict__ batch,
                                                   float* __restrict__ sums,
                                                   float* __restrict__ cnts) {
  __shared__ int sb[128];
  int n0 = blockIdx.x * 128;
  int j = threadIdx.x;
  int count = min(128, NN - n0);
  if (count <= 0) return;
  for (int t = threadIdx.x; t < count; t += 256) sb[t] = batch[n0 + t];
  __syncthreads();
  float acc = 0.f;
  int run = 0;
  int cur = sb[0];
  for (int i = 0; i < count; ++i) {
    int b = sb[i];
    if (b != cur) {
      atomicAdd(&sums[(size_t)cur * 256 + j], acc);
      if (j == 0) atomicAdd(&cnts[cur], (float)run);
      acc = 0.f;
      run = 0;
      cur = b;
    }
    acc += bf2f(h[(size_t)(n0 + i) * 256 + j]);
    run++;
  }
  atomicAdd(&sums[(size_t)cur * 256 + j], acc);
  if (j == 0) atomicAdd(&cnts[cur], (float)run);
}

// ---------- post-MLP head: one block per graph ----------
__global__ __launch_bounds__(128) void head_kernel(const float* __restrict__ sums,
                                                   const float* __restrict__ cnts,
                                                   const float* __restrict__ p1_w,
                                                   const float* __restrict__ p1_b,
                                                   const float* __restrict__ ln_g,
                                                   const float* __restrict__ ln_b,
                                                   const float* __restrict__ p2_w,
                                                   const float* __restrict__ p2_b,
                                                   const float* __restrict__ hc_w,
                                                   const float* __restrict__ hc_b,
                                                   const float* __restrict__ hf_w,
                                                   const float* __restrict__ hf_b,
                                                   float* __restrict__ out) {
  int g = blockIdx.x;
  int j = threadIdx.x;  // 0..127
  __shared__ float sp[256], st[128], sz[64];
  float cnt = fmaxf(cnts[g], 1.0f);
  for (int t = j; t < 256; t += 128) sp[t] = sums[(size_t)g * 256 + t] / cnt;
  __syncthreads();
  float acc = p1_b[j];
  for (int k = 0; k < 256; k++) acc += sp[k] * p1_w[(size_t)k * 128 + j];
  st[j] = acc;
  __syncthreads();
  float mu = 0.f;
  for (int k = 0; k < 128; k++) mu += st[k];
  mu *= (1.f / 128.f);
  float var = 0.f;
  for (int k = 0; k < 128; k++) {
    float d = st[k] - mu;
    var += d * d;
  }
  var *= (1.f / 128.f);
  float tj = (acc - mu) * rsqrtf(var + 1e-5f) * ln_g[j] + ln_b[j];
  tj = fmaxf(tj, 0.f);
  __syncthreads();
  st[j] = tj;
  __syncthreads();
  if (j < 64) {
    float z = p2_b[j];
    for (int k = 0; k < 128; k++) z += st[k] * p2_w[(size_t)k * 64 + j];
    z = fmaxf(z, 0.f);
    sz[j] = z;
    out[500 + (size_t)g * 64 + j] = z;  // output 2: z [B,64]
  }
  __syncthreads();
  if (j == 0) {
    float c = hc_b[0];
    for (int k = 0; k < 64; k++) c += sz[k] * hc_w[k];
    out[g] = c;  // output 0: cooling [B]
  }
  if (j >= 1 && j < 10) {
    int f = j - 1;
    float v = hf_b[f];
    for (int k = 0; k < 64; k++) v += sz[k] * hf_w[(size_t)k * 9 + f];
    out[50 + (size_t)g * 9 + f] = v;  // output 1: fatigue [B,9]
  }
}

extern "C" void kernel_launch(void* const* d_in, const int* in_sizes, int n_in,
                              void* d_out, int out_size, void* d_ws, size_t ws_size,
                              hipStream_t stream) {
  const float* x = (const float*)d_in[0];
  const int* ei = (const int*)d_in[1];
  const float* ea = (const float*)d_in[2];
  const int* batch = (const int*)d_in[3];
  const float* enc_w = (const float*)d_in[4];
  const float* enc_b = (const float*)d_in[5];
  const float* g1_wl = (const float*)d_in[6];
  const float* g1_bl = (const float*)d_in[7];
  const float* g1_wr = (const float*)d_in[8];
  const float* g1_br = (const float*)d_in[9];
  const float* g1_we = (const float*)d_in[10];
  const float* g1_att = (const float*)d_in[11];
  const float* g1_bias = (const float*)d_in[12];
  const float* g2_wl = (const float*)d_in[13];
  const float* g2_bl = (const float*)d_in[14];
  const float* g2_wr = (const float*)d_in[15];
  const float* g2_br = (const float*)d_in[16];
  const float* g2_we = (const float*)d_in[17];
  const float* g2_att = (const float*)d_in[18];
  const float* g2_bias = (const float*)d_in[19];
  const float* p1_w = (const float*)d_in[20];
  const float* p1_b = (const float*)d_in[21];
  const float* ln_g = (const float*)d_in[22];
  const float* ln_b = (const float*)d_in[23];
  const float* p2_w = (const float*)d_in[24];
  const float* p2_b = (const float*)d_in[25];
  const float* hc_w = (const float*)d_in[26];
  const float* hc_b = (const float*)d_in[27];
  const float* hf_w = (const float*)d_in[28];
  const float* hf_b = (const float*)d_in[29];
  float* out = (float*)d_out;

  // ---- workspace layout ----
  ushort* xlb = (ushort*)d_ws;               // N*256 bf16
  ushort* xrb = xlb + (size_t)NN * 256;      // N*256 bf16
  ushort* hb = xrb + (size_t)NN * 256;       // N*256 bf16
  ushort* h0b = hb + (size_t)NN * 256;       // N*64 bf16
  ushort* w1l = h0b + (size_t)NN * 64;       // 256*64 bf16 (transposed)
  ushort* w1r = w1l + 256 * 64;
  ushort* w2l = w1r + 256 * 64;              // 256*256 bf16
  ushort* w2r = w2l + 256 * 256;
  float* sea = (float*)(w2r + 256 * 256);    // EP
  int* ssrc = (int*)(sea + EP);              // EP
  int* counts = ssrc + EP;                   // NN
  int* offsets = counts + NN;                // NN
  int* cursor = offsets + NN;                // NN
  int* bsum = cursor + NN;                   // NBLK_SCAN
  float* sums = (float*)(bsum + NBLK_SCAN);  // B*256
  float* cnts = sums + (size_t)NB * 256;     // B
  float* esum = cnts + NB;                   // 1

  // ---- edge_attr mean ----
  hipMemsetAsync(esum, 0, sizeof(float), stream);
  reduce_sum_kernel<<<256, 256, 0, stream>>>(ea, esum);

  // ---- counting sort of edges by dst (graph static: reused by both layers) ----
  hipMemsetAsync(counts, 0, (size_t)NN * sizeof(int), stream);
  hist_kernel<<<1024, 256, 0, stream>>>(ei, counts);
  scanA_kernel<<<NBLK_SCAN, 256, 0, stream>>>(counts, bsum);
  scanB_kernel<<<1, 64, 0, stream>>>(bsum);
  scanC_kernel<<<NBLK_SCAN, 256, 0, stream>>>(counts, bsum, offsets, cursor);
  scatter_kernel<<<1024, 256, 0, stream>>>(ei, ea, esum, cursor, ssrc, sea);

  // ---- weight conversion (f32 [K][256] -> bf16 [256][K]) ----
  wconv_kernel<<<64, 256, 0, stream>>>(g1_wl, 6, w1l);
  wconv_kernel<<<64, 256, 0, stream>>>(g1_wr, 6, w1r);
  wconv_kernel<<<256, 256, 0, stream>>>(g2_wl, 8, w2l);
  wconv_kernel<<<256, 256, 0, stream>>>(g2_wr, 8, w2r);

  // ---- encoder ----
  encoder_kernel<<<(NN * 64 + 255) / 256, 256, 0, stream>>>(x, enc_w, enc_b, h0b);

  const int nGemmBlocks = (NN + 31) / 32;
  const int nGatBlocks = (NN + 3) / 4;

  // ================= GAT layer 1 (K=64) =================
  dual_linear_mfma<<<nGemmBlocks, 256, 0, stream>>>(h0b, 64, w1l, w1r, g1_bl, g1_br, xlb, xrb);
  gat_fused_kernel<<<nGatBlocks, 256, 0, stream>>>(offsets, counts, ssrc, sea, xlb, xrb,
                                                   g1_we, g1_att, g1_bias, hb);

  // ================= GAT layer 2 (K=256) =================
  dual_linear_mfma<<<nGemmBlocks, 256, 0, stream>>>(hb, 256, w2l, w2r, g2_bl, g2_br, xlb, xrb);
  gat_fused_kernel<<<nGatBlocks, 256, 0, stream>>>(offsets, counts, ssrc, sea, xlb, xrb,
                                                   g2_we, g2_att, g2_bias, hb);

  // ================= pool + head =================
  hipMemsetAsync(sums, 0, (size_t)NB * 256 * sizeof(float), stream);
  hipMemsetAsync(cnts, 0, (size_t)NB * sizeof(float), stream);
  pool_kernel<<<(NN + 127) / 128, 256, 0, stream>>>(hb, batch, sums, cnts);
  head_kernel<<<NB, 128, 0, stream>>>(sums, cnts, p1_w, p1_b, ln_g, ln_b, p2_w, p2_b,
                                      hc_w, hc_b, hf_w, hf_b, out);
}